// Round 4
// baseline (17.084 us; speedup 1.0000x reference)
//
#include <hip/hip_runtime.h>

// SAGraphPooling collapses analytically:
//   softmax over a size-1 axis == 1.0  ->  scoring is all-ones
//   stable top_k of all-equal values   ->  keep_indices = [0..1023]
// Outputs are pure slices:
//   Xs_out      = Xs[:, :1024, :]        [8,1024,128]
//   As_out      = As[:, :1024, :1024]    [8,1024,1024]
//   keep_values = ones                   [8,1024]
// => memory-bound slice-copy, ~75.5 MB HBM traffic. Floor @6.3 TB/s ~= 12 us.
//
// Two vec4 per thread (32 B/lane), no loop. Each block covers 512 vec4s;
// region boundaries (R0, R0+R1) are multiples of 512 => 3-way branch is
// block-uniform, zero divergence. Native clang vector type so the
// nontemporal builtins accept it.

typedef float f32x4 __attribute__((ext_vector_type(4)));

constexpr int B_   = 8;
constexpr int N_   = 2048;
constexpr int F_   = 128;
constexpr int KEEP = 1024;

// region sizes in f32x4 units
constexpr int R0 = B_ * KEEP * F_ / 4;     // 262144   (Xs_out)   = 512 * 512
constexpr int R1 = B_ * KEEP * KEEP / 4;   // 2097152  (As_out)   = 512 * 4096
constexpr int R2 = B_ * KEEP / 4;          // 2048     (keep_values) = 512 * 4
constexpr int TOTAL = R0 + R1 + R2;        // 2361344  = 512 * 4612

__device__ __forceinline__ f32x4 load_src(int v, const f32x4* __restrict__ Xs,
                                          const f32x4* __restrict__ As) {
    if (v < R0) {
        // Xs_out: per batch, first KEEP rows of Xs are contiguous
        const int b   = v >> 15;        // / (KEEP*F/4 = 32768)
        const int rem = v & 32767;
        return __builtin_nontemporal_load(&Xs[b * (N_ * F_ / 4) + rem]);
    } else if (v < R0 + R1) {
        // As_out: first KEEP cols of each of the first KEEP rows per batch
        const int u   = v - R0;
        const int b   = u >> 18;        // / (KEEP*KEEP/4 = 262144)
        const int rem = u & 262143;
        const int row = rem >> 8;       // / (KEEP/4 = 256)
        const int cv  = rem & 255;
        return __builtin_nontemporal_load(
            &As[b * (N_ * N_ / 4) + row * (N_ / 4) + cv]);  // strides 1048576, 512
    } else {
        const f32x4 ones = {1.0f, 1.0f, 1.0f, 1.0f};
        return ones;
    }
}

__global__ __launch_bounds__(256) void sag_pool_slice_copy(
        const f32x4* __restrict__ Xs,
        const f32x4* __restrict__ As,
        f32x4* __restrict__ out) {
    const int v0 = blockIdx.x * 512 + threadIdx.x;   // first vec4
    const int v1 = v0 + 256;                          // second vec4
    // Issue both loads before either store so they overlap.
    const f32x4 a = load_src(v0, Xs, As);
    const f32x4 b = load_src(v1, Xs, As);
    __builtin_nontemporal_store(a, &out[v0]);
    __builtin_nontemporal_store(b, &out[v1]);
}

extern "C" void kernel_launch(void* const* d_in, const int* in_sizes, int n_in,
                              void* d_out, int out_size, void* d_ws, size_t ws_size,
                              hipStream_t stream) {
    const f32x4* Xs = (const f32x4*)d_in[0];
    const f32x4* As = (const f32x4*)d_in[1];
    // d_in[2] (w0) is dead: softmax over size-1 axis is identically 1.
    f32x4* out = (f32x4*)d_out;

    sag_pool_slice_copy<<<TOTAL / 512, 256, 0, stream>>>(Xs, As, out);
}